// Round 7
// baseline (42.251 us; speedup 1.0000x reference)
//
#include <hip/hip_runtime.h>

// Problem constants (from reference)
#define BATCH     4096
#define N_CTX     8
#define N_TGT     16
#define NUM_DOCS  500
#define NUM_WORDS 8000
#define VEC_DIM   128

// Native clang vector type (accepted by __builtin_nontemporal_load).
typedef float floatx4 __attribute__((ext_vector_type(4)));

// ---------------------------------------------------------------------------
// Single fused kernel. One half-wave (32 lanes) per batch:
//
// Phase 1 (v-sliced): lane hl owns components v = 4*hl .. 4*hl+3.
//   acc = sum_c D[doc, ctx_c, v] + W[ctx_c, v]   (16 dwordx4 loads)
//
// Phase 2 (t-sliced): lane hl owns target t = hl&15 and v-half g = hl>>4.
//   Reads 64 scalars O[v][tw[t]] directly (O is 4MB -> L2/L3-hot; addresses
//   randomized across 16 random columns -> good channel spread).
//   x-values cross the v->t remap via __shfl with STATIC structure:
//   at step k4, src lane = (l&32) + (hl&16) + k4 holds acc = x[64g+4k4 .. +3].
//   One shfl_xor(16) merges the two v-halves; lanes hl<16 store 64B coalesced.
//
// No LDS, no workspace, no second dispatch, no transpose.
// ---------------------------------------------------------------------------
__global__ __launch_bounds__(256, 2) void fused_all(
    const int* __restrict__ ctx, const int* __restrict__ docs,
    const int* __restrict__ tgt, const float* __restrict__ D,
    const float* __restrict__ W, const float* __restrict__ O,
    float* __restrict__ out) {
  const int l    = threadIdx.x & 63;
  const int hl   = l & 31;
  const int wave = threadIdx.x >> 6;
  const int b    = (blockIdx.x * 4 + wave) * 2 + (l >> 5);  // 8 batches/block

  // ---- index loads ----
  const int4 c0 = *(const int4*)(ctx + b * N_CTX);
  const int4 c1 = *(const int4*)(ctx + b * N_CTX + 4);
  const int  doc = docs[b];
  const int cw[N_CTX] = {c0.x, c0.y, c0.z, c0.w, c1.x, c1.y, c1.z, c1.w};
  // Per-lane target word: lanes 0-15 and 16-31 read the same 16 ints (64B).
  const int tword = tgt[b * N_TGT + (hl & 15)];

  const float* Dbase = D + (size_t)doc * (NUM_WORDS * VEC_DIM) + 4 * hl;
  const float* Wbase = W + 4 * hl;

  // ---- phase 1: gather-sum (v-sliced, float4/lane) ----
  floatx4 dd[N_CTX], ww[N_CTX];
#pragma unroll
  for (int c = 0; c < N_CTX; ++c) {
    // D has zero intra-call reuse (2 GB): stream it past L2.
    dd[c] = __builtin_nontemporal_load(
        (const floatx4*)(Dbase + (size_t)cw[c] * VEC_DIM));
    ww[c] = *(const floatx4*)(Wbase + (size_t)cw[c] * VEC_DIM);
  }
  floatx4 acc = {0.f, 0.f, 0.f, 0.f};
#pragma unroll
  for (int c = 0; c < N_CTX; ++c) acc += dd[c] + ww[c];

  // ---- phase 2: direct O-column dot (t-sliced) ----
  const int g = hl >> 4;                 // v-half: 0 -> v in [0,64), 1 -> [64,128)
  const float* Ocol = O + tword;         // column base (stride NUM_WORDS per v)
  float p = 0.f;
#pragma unroll
  for (int k4 = 0; k4 < 16; ++k4) {
    const int src = (l & 32) + (hl & 16) + k4;  // holds x[64g+4k4 .. +3]
    const float xx = __shfl(acc.x, src, 64);
    const float xy = __shfl(acc.y, src, 64);
    const float xz = __shfl(acc.z, src, 64);
    const float xw = __shfl(acc.w, src, 64);
    const int v0 = 64 * g + 4 * k4;
    p += xx * Ocol[(size_t)(v0 + 0) * NUM_WORDS];
    p += xy * Ocol[(size_t)(v0 + 1) * NUM_WORDS];
    p += xz * Ocol[(size_t)(v0 + 2) * NUM_WORDS];
    p += xw * Ocol[(size_t)(v0 + 3) * NUM_WORDS];
  }
  // Merge the two v-halves (lanes hl and hl^16 share target hl&15).
  p += __shfl_xor(p, 16, 64);

  // Lanes hl<16 store the batch's 16 results: 64B coalesced per half-wave.
  if ((hl & 16) == 0) out[b * N_TGT + hl] = p;
}

extern "C" void kernel_launch(void* const* d_in, const int* in_sizes, int n_in,
                              void* d_out, int out_size, void* d_ws, size_t ws_size,
                              hipStream_t stream) {
  const int*   ctx  = (const int*)d_in[0];    // (4096, 8)
  const int*   docs = (const int*)d_in[1];    // (4096,)
  const int*   tgt  = (const int*)d_in[2];    // (4096, 16)
  const float* D    = (const float*)d_in[3];  // (500, 8000, 128)
  const float* W    = (const float*)d_in[4];  // (8000, 128)
  const float* O    = (const float*)d_in[5];  // (128, 8000)
  float*       out  = (float*)d_out;          // (4096, 16)

  fused_all<<<dim3(BATCH / 8), dim3(256), 0, stream>>>(
      ctx, docs, tgt, D, W, O, out);
}